// Round 1
// baseline (124.257 us; speedup 1.0000x reference)
//
#include <hip/hip_runtime.h>
#include <hip/hip_fp16.h>
#include <math.h>

// ConditionalSigKerMMDDiscriminator — x,y,z: (64,33,8) fp32 -> scalar fp32.
//
//   K      = sigker(rbf(x,x))   [symmetric]   1040 wave-items (2 pairs each)
//   L_gen  = sigker(lin(y,y))   [symmetric]   1040 items
//   L_true = sigker(lin(z,z))   [symmetric]   1040 items
//   L_mix  = sigker(lin(y,z))   [full]        2048 items
//   Kinv   = (K+I)^-1;  K*Kinv = I - Kinv  =>  W = Kinv - Kinv^2 (symmetric)
//   out    = sum_ij W[i][j]*(Lg+Lt-2Lm)[i][j]
//
// r16 fusion: K items are now waves of the SAME launch as the L items
// (they are only 20% of the PDE work and previously ran alone, latency-bound,
// for ~8us before K2 could start). Block 0 = Gauss-Jordan of (K+I): it
// spin-waits on a device-scope counter until all 1040 K items have been
// published (threadfence release on writers, acquire on reader), then runs
// the r11-proven GJ verbatim. Only block 0 ever waits -> deadlock-free under
// any dispatch order. Trace stays a separate launch (kernel boundary gives
// coherence for Lg/Lt/Lm/Kinv).
//
// pde_item's two __syncthreads are replaced by wave-local s_waitcnt
// lgkmcnt(0): the LDS slices are wave-private, so the 8 waves per block
// need no rendezvous.
//
// ws floats: [0]=K [4096]=Lg [8192]=Lt [12288]=Lm [16384]=Kinv

#define SLEN 33
#define K_ITEMS 1040

// K-item completion counter. Zero at module load; the GJ block resets it
// after its acquire, so every graph replay starts from 0.
__device__ int g_kcnt = 0;

__device__ __forceinline__ float rl(float v, int lane) {
    return __int_as_float(__builtin_amdgcn_readlane(__float_as_int(v), lane));
}

// Wave-private LDS producer->consumer sync: lanes run in lockstep, so
// draining lgkm makes all 64 lanes' ds_writes visible to the wave.
__device__ __forceinline__ void wave_lds_sync() {
    asm volatile("s_waitcnt lgkmcnt(0)" ::: "memory");
}

// ---------------------------------------------------------------------------
// One wave-item: 2 signature-kernel pairs (r6/r11-proven 2x2-block wavefront
// PDE, verbatim; LDS slices are wave-private).
// ---------------------------------------------------------------------------
__device__ __forceinline__ void pde_item(int g, int loc,
                                         const float* __restrict__ x,
                                         const float* __restrict__ y,
                                         const float* __restrict__ z,
                                         float* __restrict__ ws,
                                         float4 (*Xi4)[66],
                                         __half (*incH)[1024]) {
    const int lane = threadIdx.x & 63;
    const int h = lane >> 5;        // which pair in this wave
    const int p = lane & 31;        // block-row / build-column

    int pair = 2 * loc + h, gi, gj;
    if (g == 3) {
        gi = pair >> 6; gj = pair & 63;
    } else {
        float ff = sqrtf(8.0f * (float)pair + 1.0f);
        gi = (int)((ff - 1.0f) * 0.5f);
        while ((gi + 1) * (gi + 2) / 2 <= pair) ++gi;
        while (gi * (gi + 1) / 2 > pair) --gi;
        gj = pair - gi * (gi + 1) / 2;
    }

    const float* Ap = (g == 0) ? x : ((g == 2) ? z : y);
    const float* Bp = (g == 0) ? x : ((g == 1) ? y : z);
    const float4* As = (const float4*)(Ap + gi * (SLEN * 8));
    const float4* Bs = (const float4*)(Bp + gj * (SLEN * 8));

    for (int k = p; k < 66; k += 32) Xi4[h][k] = As[k];
    float4 b0 = Bs[2*p],   b1 = Bs[2*p+1];
    float4 b2 = Bs[2*p+2], b3 = Bs[2*p+3];
    wave_lds_sync();

    if (g == 0) {
        // RBF: lane p slides down gram columns p and p+1; no gram tile.
        float nprev;
        {
            float4 a0 = Xi4[h][0], a1 = Xi4[h][1];
            float d0=a0.x-b0.x,d1=a0.y-b0.y,d2=a0.z-b0.z,d3=a0.w-b0.w;
            float d4=a1.x-b1.x,d5=a1.y-b1.y,d6=a1.z-b1.z,d7=a1.w-b1.w;
            float da = d0*d0+d1*d1+d2*d2+d3*d3+d4*d4+d5*d5+d6*d6+d7*d7;
            float e0=a0.x-b2.x,e1=a0.y-b2.y,e2=a0.z-b2.z,e3=a0.w-b2.w;
            float e4=a1.x-b3.x,e5=a1.y-b3.y,e6=a1.z-b3.z,e7=a1.w-b3.w;
            float db = e0*e0+e1*e1+e2*e2+e3*e3+e4*e4+e5*e5+e6*e6+e7*e7;
            nprev = __expf(-db) - __expf(-da);
        }
        for (int k = 1; k <= 32; ++k) {
            float4 a0 = Xi4[h][2*k], a1 = Xi4[h][2*k+1];
            float d0=a0.x-b0.x,d1=a0.y-b0.y,d2=a0.z-b0.z,d3=a0.w-b0.w;
            float d4=a1.x-b1.x,d5=a1.y-b1.y,d6=a1.z-b1.z,d7=a1.w-b1.w;
            float da = d0*d0+d1*d1+d2*d2+d3*d3+d4*d4+d5*d5+d6*d6+d7*d7;
            float e0=a0.x-b2.x,e1=a0.y-b2.y,e2=a0.z-b2.z,e3=a0.w-b2.w;
            float e4=a1.x-b3.x,e5=a1.y-b3.y,e6=a1.z-b3.z,e7=a1.w-b3.w;
            float db = e0*e0+e1*e1+e2*e2+e3*e3+e4*e4+e5*e5+e6*e6+e7*e7;
            float diffk = __expf(-db) - __expf(-da);
            incH[h][(k-1)*32 + p] = __float2half(0.25f * (diffk - nprev));
            nprev = diffk;
        }
    } else {
        // Linear: inc[k][p] = dXi[k]·dXj[p] / 4 (rank-1, no gram).
        float e0=b2.x-b0.x, e1=b2.y-b0.y, e2=b2.z-b0.z, e3=b2.w-b0.w;
        float e4=b3.x-b1.x, e5=b3.y-b1.y, e6=b3.z-b1.z, e7=b3.w-b1.w;
        float4 a0 = Xi4[h][0], a1 = Xi4[h][1];
        #pragma unroll 4
        for (int k = 0; k < 32; ++k) {
            float4 a2 = Xi4[h][2*k+2], a3 = Xi4[h][2*k+3];
            float acc = (a2.x-a0.x)*e0 + (a2.y-a0.y)*e1
                      + (a2.z-a0.z)*e2 + (a2.w-a0.w)*e3
                      + (a3.x-a1.x)*e4 + (a3.y-a1.y)*e5
                      + (a3.z-a1.z)*e6 + (a3.w-a1.w)*e7;
            incH[h][k*32 + p] = __float2half(0.25f * acc);
            a0 = a2; a1 = a3;
        }
    }
    wave_lds_sync();

    // 2x2-block anti-diagonal wavefront (verified rounds 3-14).
    float c01 = 1.0f, c10 = 1.0f, c11 = 1.0f, dcarry = 1.0f;
    const bool isrow0 = (p == 0);
    const __half* incrow = &incH[h][p * 32];
    #pragma unroll 4
    for (int m = 0; m < 63; ++m) {
        float nb10 = __shfl_up(c10, 1);
        float nb11 = __shfl_up(c11, 1);
        int t = m - p;
        float incv = __half2float(incrow[t & 31]);
        float n0 = isrow0 ? 1.0f : nb10;
        float n1 = isrow0 ? 1.0f : nb11;
        bool t0 = (t == 0);
        float w0 = t0 ? 1.0f : c01;
        float w1 = t0 ? 1.0f : c11;
        float d  = t0 ? 1.0f : dcarry;
        float i2 = incv * incv * (1.0f / 12.0f);
        float C1 = 1.0f + 0.5f * incv + i2;
        float C2 = 1.0f - i2;
        float v00 = (w0  + n0 ) * C1 - d   * C2;
        float v01 = (v00 + n1 ) * C1 - n0  * C2;
        float v10 = (v00 + w1 ) * C1 - w0  * C2;
        float v11 = (v10 + v01) * C1 - v00 * C2;
        c01 = v01; c10 = v10; c11 = v11;
        dcarry = n1;
    }

    if (p == 31) {
        float* dst = ws + g * 4096;
        dst[gi * 64 + gj] = c11;
        if (g != 3) dst[gj * 64 + gi] = c11;
    }
    if (g == 0) {
        // Publish this K item device-wide: release fence, then count it.
        __threadfence();
        if (lane == 0) atomicAdd(&g_kcnt, 1);
    }
}

// ---------------------------------------------------------------------------
// Fused kernel: 647 blocks x 512 threads.
// Block 0: spins until all K items published, then register GJ of (K+I)
// (r11-proven 2x2-pivot ping-pong scheme); writes Kinv, zeroes out[0].
// Blocks 1..646: exactly ONE PDE item per wave, 5168 items total (no tail):
//   items [0,1040) = K, [1040,2080) = Lg, [2080,3120) = Lt, [3120,5168) = Lm.
// K items live in blocks 1..130 -> first scheduling round -> GJ starts early.
// ---------------------------------------------------------------------------
__global__ __launch_bounds__(512, 4)
void fused_kernel(const float* __restrict__ x, const float* __restrict__ y,
                  const float* __restrict__ z, float* __restrict__ ws,
                  float* __restrict__ out) {
    __shared__ float4 XiS[16][66];
    __shared__ __half incS[16][1024];
    __shared__ float prow[2][2][64];

    const int b   = blockIdx.x;
    const int tid = threadIdx.x;
    const int wv  = tid >> 6;           // wave 0..7

    if (b == 0) {
        if (tid == 0) {
            out[0] = 0.0f;               // init for K3's atomicAdd
            // Wait for all 1040 K items (only this block ever waits ->
            // deadlock-free under any dispatch order).
            while (__hip_atomic_load(&g_kcnt, __ATOMIC_RELAXED,
                                     __HIP_MEMORY_SCOPE_AGENT) < K_ITEMS)
                __builtin_amdgcn_s_sleep(2);
            // All adds happened-before this point; reset for the next replay.
            __hip_atomic_store(&g_kcnt, 0, __ATOMIC_RELAXED,
                               __HIP_MEMORY_SCOPE_AGENT);
        }
        __syncthreads();
        __threadfence();                 // acquire: drop stale K cachelines

        // ---- Gauss-Jordan inverse of (K+I); thread (w,c) owns rows 8w+i ----
        const int c = tid & 63, w = wv;
        const float* K = ws;
        float* Kinv = ws + 16384;
        float m[8];
        #pragma unroll
        for (int i = 0; i < 8; ++i) {
            int r = w * 8 + i;
            m[i] = K[r * 64 + c] + ((r == c) ? 1.0f : 0.0f);
        }
        #pragma unroll 1
        for (int it = 0; it < 8; ++it) {
            #pragma unroll
            for (int j = 0; j < 4; ++j) {
                const int p0 = 8 * it + 2 * j, p1 = p0 + 1;
                const int i0 = 2 * j, i1 = i0 + 1;     // compile-time
                const int buf = j & 1;
                if (w == it) {
                    float x0 = m[i0], x1 = m[i1];
                    // 2x2 pivot block inverse (SPD principal block, det>0)
                    float a  = rl(x0, p0), bq = rl(x0, p1);
                    float cq = rl(x1, p0), dq = rl(x1, p1);
                    float dinv = 1.0f / (a * dq - bq * cq);
                    float P00 =  dq * dinv, P01 = -bq * dinv;
                    float P10 = -cq * dinv, P11 =  a  * dinv;
                    float sp0 = P00 * x0 + P01 * x1;
                    float sp1 = P10 * x0 + P11 * x1;
                    sp0 = (c == p0) ? P00 : ((c == p1) ? P01 : sp0);
                    sp1 = (c == p0) ? P10 : ((c == p1) ? P11 : sp1);
                    m[i0] = sp0; m[i1] = sp1;
                    prow[buf][0][c] = sp0;
                    prow[buf][1][c] = sp1;
                }
                __syncthreads();
                float s0  = prow[buf][0][c],  s1  = prow[buf][1][c];
                float q00 = prow[buf][0][p0], q01 = prow[buf][0][p1];
                float q10 = prow[buf][1][p0], q11 = prow[buf][1][p1];
                #pragma unroll
                for (int i = 0; i < 8; ++i) {
                    bool pivotRow = (w == it) && (i == i0 || i == i1);
                    float f0 = rl(m[i], p0);
                    float f1 = rl(m[i], p1);
                    float nv = m[i] - f0 * s0 - f1 * s1;
                    float wb0 = -(f0 * q00 + f1 * q10);
                    float wb1 = -(f0 * q01 + f1 * q11);
                    nv = (c == p0) ? wb0 : ((c == p1) ? wb1 : nv);
                    if (!pivotRow) m[i] = nv;
                }
            }
        }
        #pragma unroll
        for (int i = 0; i < 8; ++i)
            Kinv[(w * 8 + i) * 64 + c] = m[i];
    } else {
        // ---- PDE items: (b-1)*8 + wv in [0, 5168), exactly one per wave ----
        int item = (b - 1) * 8 + wv;
        int g, loc;
        if (item < 1040)      { g = 0; loc = item; }
        else if (item < 2080) { g = 1; loc = item - 1040; }
        else if (item < 3120) { g = 2; loc = item - 2080; }
        else                  { g = 3; loc = item - 3120; }
        pde_item(g, loc, x, y, z, ws, &XiS[2 * wv], &incS[2 * wv]);
    }
}

// ---------------------------------------------------------------------------
// K3: block i computes W[i][:] = Kinv[i][:] - (Kinv^2)[i][:], dotted with
// L[:,i] (r3-proven); lane 0 atomicAdds into out (zeroed by fused block 0).
// ---------------------------------------------------------------------------
__global__ __launch_bounds__(64)
void trace_kernel(const float* __restrict__ ws, float* __restrict__ out) {
    const int i    = blockIdx.x;
    const int lane = threadIdx.x;
    const float* Lg   = ws + 4096;
    const float* Lt   = ws + 8192;
    const float* Lm   = ws + 12288;
    const float* Kinv = ws + 16384;

    float u = Kinv[i * 64 + lane];
    float acc = 0.0f;
    #pragma unroll 8
    for (int k = 0; k < 64; ++k)
        acc = fmaf(__shfl(u, k), Kinv[k * 64 + lane], acc);   // (Kinv^2)[i][lane]
    float wv = u - acc;

    float lc = Lg[lane * 64 + i] + Lt[lane * 64 + i] - 2.0f * Lm[lane * 64 + i];
    float local = wv * lc;
    #pragma unroll
    for (int off = 32; off > 0; off >>= 1)
        local += __shfl_down(local, off);
    if (lane == 0) atomicAdd(out, local);
}

extern "C" void kernel_launch(void* const* d_in, const int* in_sizes, int n_in,
                              void* d_out, int out_size, void* d_ws, size_t ws_size,
                              hipStream_t stream) {
    const float* x = (const float*)d_in[0];
    const float* y = (const float*)d_in[1];
    const float* z = (const float*)d_in[2];
    float* out = (float*)d_out;
    float* ws  = (float*)d_ws;      // 20480 floats = 80 KB used

    fused_kernel<<<647, 512, 0, stream>>>(x, y, z, ws, out);
    trace_kernel<<<64, 64, 0, stream>>>(ws, out);
}

// Round 2
// 105.519 us; speedup vs baseline: 1.1776x; 1.1776x over previous
//
#include <hip/hip_runtime.h>
#include <hip/hip_fp16.h>
#include <math.h>

// ConditionalSigKerMMDDiscriminator — x,y,z: (64,33,8) fp32 -> scalar fp32.
//
//   K      = sigker(rbf(x,x))   [symmetric]   1040 wave-items (2 pairs each)
//   L_gen  = sigker(lin(y,y))   [symmetric]   1040 items
//   L_true = sigker(lin(z,z))   [symmetric]   1040 items
//   L_mix  = sigker(lin(y,z))   [full]        2048 items
//   Kinv   = (K+I)^-1;  K*Kinv = I - Kinv  =>  W = Kinv - Kinv^2 (symmetric)
//   out    = sum_ij W[i][j]*(Lg+Lt-2Lm)[i][j]
//
// r17: r16's fusion kept, but the per-K-item __threadfence() is GONE. On
// gfx950 an agent-scope fence lowers to buffer_wbl2+buffer_inv (full L2
// writeback+invalidate, bridging non-coherent per-XCD L2s); 1040 of those
// was a cache-maintenance storm (fused kernel 71us, VALUBusy 24%).
// Replacement protocol, no cache maintenance anywhere:
//   writers: K results stored with device-SCOPED relaxed atomic stores
//            (sc1 write-through to the coherent point, 2 floats/item),
//            then s_waitcnt vmcnt(0), then RELAXED device atomicAdd count.
//   reader (GJ block): relaxed poll of count; reads K via device-scoped
//            relaxed atomic loads (bypass stale L1/L2 by scope; one-time).
// Ordering: data(sc1) -> vmcnt(0) -> count-add  ==>  count==1040 implies all
// K data at the coherent point; scoped loads observe it. Only block 0 ever
// waits -> deadlock-free under any dispatch order.
//
// launch_bounds(512,6): 3 blocks/CU (LDS 3x49.5KB < 160KB) -> all 647 blocks
// co-resident in one scheduling round.
//
// ws floats: [0]=K [4096]=Lg [8192]=Lt [12288]=Lm [16384]=Kinv

#define SLEN 33
#define K_ITEMS 1040

// K-item completion counter. Zero at module load; the GJ block resets it
// after use, so every graph replay starts from 0.
__device__ int g_kcnt = 0;

__device__ __forceinline__ float rl(float v, int lane) {
    return __int_as_float(__builtin_amdgcn_readlane(__float_as_int(v), lane));
}

// Wave-private LDS producer->consumer sync: lanes run in lockstep, so
// draining lgkm makes all 64 lanes' ds_writes visible to the wave.
__device__ __forceinline__ void wave_lds_sync() {
    asm volatile("s_waitcnt lgkmcnt(0)" ::: "memory");
}

// ---------------------------------------------------------------------------
// One wave-item: 2 signature-kernel pairs (r6/r11-proven 2x2-block wavefront
// PDE, verbatim; LDS slices are wave-private).
// ---------------------------------------------------------------------------
__device__ __forceinline__ void pde_item(int g, int loc,
                                         const float* __restrict__ x,
                                         const float* __restrict__ y,
                                         const float* __restrict__ z,
                                         float* __restrict__ ws,
                                         float4 (*Xi4)[66],
                                         __half (*incH)[1024]) {
    const int lane = threadIdx.x & 63;
    const int h = lane >> 5;        // which pair in this wave
    const int p = lane & 31;        // block-row / build-column

    int pair = 2 * loc + h, gi, gj;
    if (g == 3) {
        gi = pair >> 6; gj = pair & 63;
    } else {
        float ff = sqrtf(8.0f * (float)pair + 1.0f);
        gi = (int)((ff - 1.0f) * 0.5f);
        while ((gi + 1) * (gi + 2) / 2 <= pair) ++gi;
        while (gi * (gi + 1) / 2 > pair) --gi;
        gj = pair - gi * (gi + 1) / 2;
    }

    const float* Ap = (g == 0) ? x : ((g == 2) ? z : y);
    const float* Bp = (g == 0) ? x : ((g == 1) ? y : z);
    const float4* As = (const float4*)(Ap + gi * (SLEN * 8));
    const float4* Bs = (const float4*)(Bp + gj * (SLEN * 8));

    for (int k = p; k < 66; k += 32) Xi4[h][k] = As[k];
    float4 b0 = Bs[2*p],   b1 = Bs[2*p+1];
    float4 b2 = Bs[2*p+2], b3 = Bs[2*p+3];
    wave_lds_sync();

    if (g == 0) {
        // RBF: lane p slides down gram columns p and p+1; no gram tile.
        float nprev;
        {
            float4 a0 = Xi4[h][0], a1 = Xi4[h][1];
            float d0=a0.x-b0.x,d1=a0.y-b0.y,d2=a0.z-b0.z,d3=a0.w-b0.w;
            float d4=a1.x-b1.x,d5=a1.y-b1.y,d6=a1.z-b1.z,d7=a1.w-b1.w;
            float da = d0*d0+d1*d1+d2*d2+d3*d3+d4*d4+d5*d5+d6*d6+d7*d7;
            float e0=a0.x-b2.x,e1=a0.y-b2.y,e2=a0.z-b2.z,e3=a0.w-b2.w;
            float e4=a1.x-b3.x,e5=a1.y-b3.y,e6=a1.z-b3.z,e7=a1.w-b3.w;
            float db = e0*e0+e1*e1+e2*e2+e3*e3+e4*e4+e5*e5+e6*e6+e7*e7;
            nprev = __expf(-db) - __expf(-da);
        }
        for (int k = 1; k <= 32; ++k) {
            float4 a0 = Xi4[h][2*k], a1 = Xi4[h][2*k+1];
            float d0=a0.x-b0.x,d1=a0.y-b0.y,d2=a0.z-b0.z,d3=a0.w-b0.w;
            float d4=a1.x-b1.x,d5=a1.y-b1.y,d6=a1.z-b1.z,d7=a1.w-b1.w;
            float da = d0*d0+d1*d1+d2*d2+d3*d3+d4*d4+d5*d5+d6*d6+d7*d7;
            float e0=a0.x-b2.x,e1=a0.y-b2.y,e2=a0.z-b2.z,e3=a0.w-b2.w;
            float e4=a1.x-b3.x,e5=a1.y-b3.y,e6=a1.z-b3.z,e7=a1.w-b3.w;
            float db = e0*e0+e1*e1+e2*e2+e3*e3+e4*e4+e5*e5+e6*e6+e7*e7;
            float diffk = __expf(-db) - __expf(-da);
            incH[h][(k-1)*32 + p] = __float2half(0.25f * (diffk - nprev));
            nprev = diffk;
        }
    } else {
        // Linear: inc[k][p] = dXi[k]·dXj[p] / 4 (rank-1, no gram).
        float e0=b2.x-b0.x, e1=b2.y-b0.y, e2=b2.z-b0.z, e3=b2.w-b0.w;
        float e4=b3.x-b1.x, e5=b3.y-b1.y, e6=b3.z-b1.z, e7=b3.w-b1.w;
        float4 a0 = Xi4[h][0], a1 = Xi4[h][1];
        #pragma unroll 4
        for (int k = 0; k < 32; ++k) {
            float4 a2 = Xi4[h][2*k+2], a3 = Xi4[h][2*k+3];
            float acc = (a2.x-a0.x)*e0 + (a2.y-a0.y)*e1
                      + (a2.z-a0.z)*e2 + (a2.w-a0.w)*e3
                      + (a3.x-a1.x)*e4 + (a3.y-a1.y)*e5
                      + (a3.z-a1.z)*e6 + (a3.w-a1.w)*e7;
            incH[h][k*32 + p] = __float2half(0.25f * acc);
            a0 = a2; a1 = a3;
        }
    }
    wave_lds_sync();

    // 2x2-block anti-diagonal wavefront (verified rounds 3-14).
    float c01 = 1.0f, c10 = 1.0f, c11 = 1.0f, dcarry = 1.0f;
    const bool isrow0 = (p == 0);
    const __half* incrow = &incH[h][p * 32];
    #pragma unroll 4
    for (int m = 0; m < 63; ++m) {
        float nb10 = __shfl_up(c10, 1);
        float nb11 = __shfl_up(c11, 1);
        int t = m - p;
        float incv = __half2float(incrow[t & 31]);
        float n0 = isrow0 ? 1.0f : nb10;
        float n1 = isrow0 ? 1.0f : nb11;
        bool t0 = (t == 0);
        float w0 = t0 ? 1.0f : c01;
        float w1 = t0 ? 1.0f : c11;
        float d  = t0 ? 1.0f : dcarry;
        float i2 = incv * incv * (1.0f / 12.0f);
        float C1 = 1.0f + 0.5f * incv + i2;
        float C2 = 1.0f - i2;
        float v00 = (w0  + n0 ) * C1 - d   * C2;
        float v01 = (v00 + n1 ) * C1 - n0  * C2;
        float v10 = (v00 + w1 ) * C1 - w0  * C2;
        float v11 = (v10 + v01) * C1 - v00 * C2;
        c01 = v01; c10 = v10; c11 = v11;
        dcarry = n1;
    }

    if (g == 0) {
        // K results must be visible cross-XCD before the counter bump:
        // device-scoped relaxed stores (sc1 -> coherent point, no cache
        // maintenance), then wait for write ack, then relaxed count.
        if (p == 31) {
            __hip_atomic_store(&ws[gi * 64 + gj], c11, __ATOMIC_RELAXED,
                               __HIP_MEMORY_SCOPE_AGENT);
            __hip_atomic_store(&ws[gj * 64 + gi], c11, __ATOMIC_RELAXED,
                               __HIP_MEMORY_SCOPE_AGENT);
        }
        asm volatile("s_waitcnt vmcnt(0)" ::: "memory");
        if (lane == 0)
            __hip_atomic_fetch_add(&g_kcnt, 1, __ATOMIC_RELAXED,
                                   __HIP_MEMORY_SCOPE_AGENT);
    } else {
        if (p == 31) {
            float* dst = ws + g * 4096;
            dst[gi * 64 + gj] = c11;
            if (g != 3) dst[gj * 64 + gi] = c11;
        }
    }
}

// ---------------------------------------------------------------------------
// Fused kernel: 647 blocks x 512 threads, 3 blocks/CU (all co-resident).
// Block 0: spins until all K items published, then register GJ of (K+I)
// (r11-proven 2x2-pivot ping-pong scheme); writes Kinv, zeroes out[0].
// Blocks 1..646: exactly ONE PDE item per wave, 5168 items total (no tail):
//   items [0,1040) = K, [1040,2080) = Lg, [2080,3120) = Lt, [3120,5168) = Lm.
// K items live in blocks 1..130 -> first scheduling round -> GJ starts early.
// ---------------------------------------------------------------------------
__global__ __launch_bounds__(512, 6)
void fused_kernel(const float* __restrict__ x, const float* __restrict__ y,
                  const float* __restrict__ z, float* __restrict__ ws,
                  float* __restrict__ out) {
    __shared__ float4 XiS[16][66];
    __shared__ __half incS[16][1024];
    __shared__ float prow[2][2][64];

    const int b   = blockIdx.x;
    const int tid = threadIdx.x;
    const int wv  = tid >> 6;           // wave 0..7

    if (b == 0) {
        if (tid == 0) {
            out[0] = 0.0f;               // init for trace's atomicAdd
            // Wait for all 1040 K items (only this block ever waits ->
            // deadlock-free under any dispatch order).
            while (__hip_atomic_load(&g_kcnt, __ATOMIC_RELAXED,
                                     __HIP_MEMORY_SCOPE_AGENT) < K_ITEMS)
                __builtin_amdgcn_s_sleep(2);
            // All adds happened-before this point; reset for the next replay.
            __hip_atomic_store(&g_kcnt, 0, __ATOMIC_RELAXED,
                               __HIP_MEMORY_SCOPE_AGENT);
        }
        __syncthreads();

        // ---- Gauss-Jordan inverse of (K+I); thread (w,c) owns rows 8w+i ----
        // K is read with device-scoped loads (bypass possibly-stale L1/L2;
        // one-time cost, 8 dwords/thread, pipelined).
        const int c = tid & 63, w = wv;
        const float* K = ws;
        float* Kinv = ws + 16384;
        float m[8];
        #pragma unroll
        for (int i = 0; i < 8; ++i) {
            int r = w * 8 + i;
            m[i] = __hip_atomic_load(&K[r * 64 + c], __ATOMIC_RELAXED,
                                     __HIP_MEMORY_SCOPE_AGENT)
                 + ((r == c) ? 1.0f : 0.0f);
        }
        #pragma unroll 1
        for (int it = 0; it < 8; ++it) {
            #pragma unroll
            for (int j = 0; j < 4; ++j) {
                const int p0 = 8 * it + 2 * j, p1 = p0 + 1;
                const int i0 = 2 * j, i1 = i0 + 1;     // compile-time
                const int buf = j & 1;
                if (w == it) {
                    float x0 = m[i0], x1 = m[i1];
                    // 2x2 pivot block inverse (SPD principal block, det>0)
                    float a  = rl(x0, p0), bq = rl(x0, p1);
                    float cq = rl(x1, p0), dq = rl(x1, p1);
                    float dinv = 1.0f / (a * dq - bq * cq);
                    float P00 =  dq * dinv, P01 = -bq * dinv;
                    float P10 = -cq * dinv, P11 =  a  * dinv;
                    float sp0 = P00 * x0 + P01 * x1;
                    float sp1 = P10 * x0 + P11 * x1;
                    sp0 = (c == p0) ? P00 : ((c == p1) ? P01 : sp0);
                    sp1 = (c == p0) ? P10 : ((c == p1) ? P11 : sp1);
                    m[i0] = sp0; m[i1] = sp1;
                    prow[buf][0][c] = sp0;
                    prow[buf][1][c] = sp1;
                }
                __syncthreads();
                float s0  = prow[buf][0][c],  s1  = prow[buf][1][c];
                float q00 = prow[buf][0][p0], q01 = prow[buf][0][p1];
                float q10 = prow[buf][1][p0], q11 = prow[buf][1][p1];
                #pragma unroll
                for (int i = 0; i < 8; ++i) {
                    bool pivotRow = (w == it) && (i == i0 || i == i1);
                    float f0 = rl(m[i], p0);
                    float f1 = rl(m[i], p1);
                    float nv = m[i] - f0 * s0 - f1 * s1;
                    float wb0 = -(f0 * q00 + f1 * q10);
                    float wb1 = -(f0 * q01 + f1 * q11);
                    nv = (c == p0) ? wb0 : ((c == p1) ? wb1 : nv);
                    if (!pivotRow) m[i] = nv;
                }
            }
        }
        #pragma unroll
        for (int i = 0; i < 8; ++i)
            Kinv[(w * 8 + i) * 64 + c] = m[i];
    } else {
        // ---- PDE items: (b-1)*8 + wv in [0, 5168), exactly one per wave ----
        int item = (b - 1) * 8 + wv;
        int g, loc;
        if (item < 1040)      { g = 0; loc = item; }
        else if (item < 2080) { g = 1; loc = item - 1040; }
        else if (item < 3120) { g = 2; loc = item - 2080; }
        else                  { g = 3; loc = item - 3120; }
        pde_item(g, loc, x, y, z, ws, &XiS[2 * wv], &incS[2 * wv]);
    }
}

// ---------------------------------------------------------------------------
// Trace: block i computes W[i][:] = Kinv[i][:] - (Kinv^2)[i][:], dotted with
// L[:,i] (r3-proven); lane 0 atomicAdds into out (zeroed by fused block 0).
// ---------------------------------------------------------------------------
__global__ __launch_bounds__(64)
void trace_kernel(const float* __restrict__ ws, float* __restrict__ out) {
    const int i    = blockIdx.x;
    const int lane = threadIdx.x;
    const float* Lg   = ws + 4096;
    const float* Lt   = ws + 8192;
    const float* Lm   = ws + 12288;
    const float* Kinv = ws + 16384;

    float u = Kinv[i * 64 + lane];
    float acc = 0.0f;
    #pragma unroll 8
    for (int k = 0; k < 64; ++k)
        acc = fmaf(__shfl(u, k), Kinv[k * 64 + lane], acc);   // (Kinv^2)[i][lane]
    float wv = u - acc;

    float lc = Lg[lane * 64 + i] + Lt[lane * 64 + i] - 2.0f * Lm[lane * 64 + i];
    float local = wv * lc;
    #pragma unroll
    for (int off = 32; off > 0; off >>= 1)
        local += __shfl_down(local, off);
    if (lane == 0) atomicAdd(out, local);
}

extern "C" void kernel_launch(void* const* d_in, const int* in_sizes, int n_in,
                              void* d_out, int out_size, void* d_ws, size_t ws_size,
                              hipStream_t stream) {
    const float* x = (const float*)d_in[0];
    const float* y = (const float*)d_in[1];
    const float* z = (const float*)d_in[2];
    float* out = (float*)d_out;
    float* ws  = (float*)d_ws;      // 20480 floats = 80 KB used

    fused_kernel<<<647, 512, 0, stream>>>(x, y, z, ws, out);
    trace_kernel<<<64, 64, 0, stream>>>(ws, out);
}

// Round 4
// 100.241 us; speedup vs baseline: 1.2396x; 1.0527x over previous
//
#include <hip/hip_runtime.h>
#include <hip/hip_fp16.h>
#include <math.h>

// ConditionalSigKerMMDDiscriminator — x,y,z: (64,33,8) fp32 -> scalar fp32.
//
//   K      = sigker(rbf(x,x))   [symmetric]   1040 wave-items (2 pairs each)
//   L_gen  = sigker(lin(y,y))   [symmetric]   1040 items
//   L_true = sigker(lin(z,z))   [symmetric]   1040 items
//   L_mix  = sigker(lin(y,z))   [full]        2048 items
//   Kinv   = (K+I)^-1;  K*Kinv = I - Kinv  =>  W = Kinv - Kinv^2 (symmetric)
//   out    = sum_ij W[i][j]*(Lg+Lt-2Lm)[i][j]
//
// r19 = r18 resubmitted verbatim (r18's bench failed on container acquisition,
// not on the kernel — no counters to learn from).
//
// r18: REVERT of the r16/r17 single-launch fusion. Two rounds proved the
// fused structure runs the same PDE work 4x slower (71-75us, occupancy 17%,
// VALUBusy 23%) regardless of fence strategy — the split r15 schedule, whose
// post-fill tail is only K2+K3, is strictly better on this harness.
// One change vs r15: K2 launch_bounds (512,4)->(512,6). At 2 blocks/CU the
// 517-block grid needed a 5-block SECOND scheduling round (~5-7us straggler
// on K2's span); at a 3 blocks/CU cap all 517 place in round one while the
// scheduler still spreads ~2/CU (517/256), so contention is unchanged.
// Safety pre-verified in r17: this exact GJ+PDE code compiled at 6 waves/EU
// with VGPR=40, no scratch traffic, bit-identical absmax.
//
// K1: pde for K only (1040 x 64-thr blocks, r6/r11-proven config).
// K2: 517 x 512-thr blocks: block 0 = register GJ of (K+I) hidden behind L;
//     blocks 1..516 = exactly ONE L item per wave (4128 exact — no tail).
// K3: 64-block trace, atomicAdd into out.
//
// ws floats: [0]=K [4096]=Lg [8192]=Lt [12288]=Lm [16384]=Kinv

#define SLEN 33

__device__ __forceinline__ float rl(float v, int lane) {
    return __int_as_float(__builtin_amdgcn_readlane(__float_as_int(v), lane));
}

// ---------------------------------------------------------------------------
// One wave-item: 2 signature-kernel pairs (r6/r11-proven 2x2-block wavefront
// PDE, verbatim; LDS slices are wave-private).
// ---------------------------------------------------------------------------
__device__ __forceinline__ void pde_item(int g, int loc,
                                         const float* __restrict__ x,
                                         const float* __restrict__ y,
                                         const float* __restrict__ z,
                                         float* __restrict__ ws,
                                         float4 (*Xi4)[66],
                                         __half (*incH)[1024]) {
    const int lane = threadIdx.x & 63;
    const int h = lane >> 5;        // which pair in this wave
    const int p = lane & 31;        // block-row / build-column

    int pair = 2 * loc + h, gi, gj;
    if (g == 3) {
        gi = pair >> 6; gj = pair & 63;
    } else {
        float ff = sqrtf(8.0f * (float)pair + 1.0f);
        gi = (int)((ff - 1.0f) * 0.5f);
        while ((gi + 1) * (gi + 2) / 2 <= pair) ++gi;
        while (gi * (gi + 1) / 2 > pair) --gi;
        gj = pair - gi * (gi + 1) / 2;
    }

    const float* Ap = (g == 0) ? x : ((g == 2) ? z : y);
    const float* Bp = (g == 0) ? x : ((g == 1) ? y : z);
    const float4* As = (const float4*)(Ap + gi * (SLEN * 8));
    const float4* Bs = (const float4*)(Bp + gj * (SLEN * 8));

    for (int k = p; k < 66; k += 32) Xi4[h][k] = As[k];
    float4 b0 = Bs[2*p],   b1 = Bs[2*p+1];
    float4 b2 = Bs[2*p+2], b3 = Bs[2*p+3];
    __syncthreads();

    if (g == 0) {
        // RBF: lane p slides down gram columns p and p+1; no gram tile.
        float nprev;
        {
            float4 a0 = Xi4[h][0], a1 = Xi4[h][1];
            float d0=a0.x-b0.x,d1=a0.y-b0.y,d2=a0.z-b0.z,d3=a0.w-b0.w;
            float d4=a1.x-b1.x,d5=a1.y-b1.y,d6=a1.z-b1.z,d7=a1.w-b1.w;
            float da = d0*d0+d1*d1+d2*d2+d3*d3+d4*d4+d5*d5+d6*d6+d7*d7;
            float e0=a0.x-b2.x,e1=a0.y-b2.y,e2=a0.z-b2.z,e3=a0.w-b2.w;
            float e4=a1.x-b3.x,e5=a1.y-b3.y,e6=a1.z-b3.z,e7=a1.w-b3.w;
            float db = e0*e0+e1*e1+e2*e2+e3*e3+e4*e4+e5*e5+e6*e6+e7*e7;
            nprev = __expf(-db) - __expf(-da);
        }
        for (int k = 1; k <= 32; ++k) {
            float4 a0 = Xi4[h][2*k], a1 = Xi4[h][2*k+1];
            float d0=a0.x-b0.x,d1=a0.y-b0.y,d2=a0.z-b0.z,d3=a0.w-b0.w;
            float d4=a1.x-b1.x,d5=a1.y-b1.y,d6=a1.z-b1.z,d7=a1.w-b1.w;
            float da = d0*d0+d1*d1+d2*d2+d3*d3+d4*d4+d5*d5+d6*d6+d7*d7;
            float e0=a0.x-b2.x,e1=a0.y-b2.y,e2=a0.z-b2.z,e3=a0.w-b2.w;
            float e4=a1.x-b3.x,e5=a1.y-b3.y,e6=a1.z-b3.z,e7=a1.w-b3.w;
            float db = e0*e0+e1*e1+e2*e2+e3*e3+e4*e4+e5*e5+e6*e6+e7*e7;
            float diffk = __expf(-db) - __expf(-da);
            incH[h][(k-1)*32 + p] = __float2half(0.25f * (diffk - nprev));
            nprev = diffk;
        }
    } else {
        // Linear: inc[k][p] = dXi[k]·dXj[p] / 4 (rank-1, no gram).
        float e0=b2.x-b0.x, e1=b2.y-b0.y, e2=b2.z-b0.z, e3=b2.w-b0.w;
        float e4=b3.x-b1.x, e5=b3.y-b1.y, e6=b3.z-b1.z, e7=b3.w-b1.w;
        float4 a0 = Xi4[h][0], a1 = Xi4[h][1];
        #pragma unroll 4
        for (int k = 0; k < 32; ++k) {
            float4 a2 = Xi4[h][2*k+2], a3 = Xi4[h][2*k+3];
            float acc = (a2.x-a0.x)*e0 + (a2.y-a0.y)*e1
                      + (a2.z-a0.z)*e2 + (a2.w-a0.w)*e3
                      + (a3.x-a1.x)*e4 + (a3.y-a1.y)*e5
                      + (a3.z-a1.z)*e6 + (a3.w-a1.w)*e7;
            incH[h][k*32 + p] = __float2half(0.25f * acc);
            a0 = a2; a1 = a3;
        }
    }
    __syncthreads();

    // 2x2-block anti-diagonal wavefront (verified rounds 3-14).
    float c01 = 1.0f, c10 = 1.0f, c11 = 1.0f, dcarry = 1.0f;
    const bool isrow0 = (p == 0);
    const __half* incrow = &incH[h][p * 32];
    #pragma unroll 4
    for (int m = 0; m < 63; ++m) {
        float nb10 = __shfl_up(c10, 1);
        float nb11 = __shfl_up(c11, 1);
        int t = m - p;
        float incv = __half2float(incrow[t & 31]);
        float n0 = isrow0 ? 1.0f : nb10;
        float n1 = isrow0 ? 1.0f : nb11;
        bool t0 = (t == 0);
        float w0 = t0 ? 1.0f : c01;
        float w1 = t0 ? 1.0f : c11;
        float d  = t0 ? 1.0f : dcarry;
        float i2 = incv * incv * (1.0f / 12.0f);
        float C1 = 1.0f + 0.5f * incv + i2;
        float C2 = 1.0f - i2;
        float v00 = (w0  + n0 ) * C1 - d   * C2;
        float v01 = (v00 + n1 ) * C1 - n0  * C2;
        float v10 = (v00 + w1 ) * C1 - w0  * C2;
        float v11 = (v10 + v01) * C1 - v00 * C2;
        c01 = v01; c10 = v10; c11 = v11;
        dcarry = n1;
    }

    if (p == 31) {
        float* dst = ws + g * 4096;
        dst[gi * 64 + gj] = c11;
        if (g != 3) dst[gj * 64 + gi] = c11;
    }
}

// ---------------------------------------------------------------------------
// K1: K gram only (g=0). 1040 blocks x 64 threads (r6/r11-proven config).
// ---------------------------------------------------------------------------
__global__ __launch_bounds__(64, 5)
void pdeK_kernel(const float* __restrict__ x, const float* __restrict__ y,
                 const float* __restrict__ z, float* __restrict__ ws) {
    __shared__ float4 XiS[2][66];
    __shared__ __half incS[2][1024];
    pde_item(0, blockIdx.x, x, y, z, ws, XiS, incS);
}

// ---------------------------------------------------------------------------
// K2: 517 blocks x 512 threads. launch_bounds(512,6): 3 blocks/CU cap so all
// 517 blocks place in ONE scheduling round (was 512+5 at the (512,4) cap —
// a ~5-7us straggler round on the kernel's span). Scheduler still spreads
// ~2 blocks/CU (517/256), so per-SIMD contention is unchanged.
// Block 0: register GJ of (K+I), hidden behind L; writes Kinv, zeroes out.
// Blocks 1..516: exactly one L item per wave (4128 items total — no tail).
// ---------------------------------------------------------------------------
__global__ __launch_bounds__(512, 6)
void pdeL_gj_kernel(const float* __restrict__ x, const float* __restrict__ y,
                    const float* __restrict__ z, float* __restrict__ ws,
                    float* __restrict__ out) {
    __shared__ float4 XiS[16][66];
    __shared__ __half incS[16][1024];
    __shared__ float prow[2][2][64];

    const int b   = blockIdx.x;
    const int tid = threadIdx.x;
    const int wv  = tid >> 6;           // wave 0..7

    if (b == 0) {
        // ---- Gauss-Jordan inverse of (K+I); thread (w,c) owns rows 8w+i ----
        const int c = tid & 63, w = wv;
        const float* K = ws;
        float* Kinv = ws + 16384;
        float m[8];
        #pragma unroll
        for (int i = 0; i < 8; ++i) {
            int r = w * 8 + i;
            m[i] = K[r * 64 + c] + ((r == c) ? 1.0f : 0.0f);
        }
        #pragma unroll 1
        for (int it = 0; it < 8; ++it) {
            #pragma unroll
            for (int j = 0; j < 4; ++j) {
                const int p0 = 8 * it + 2 * j, p1 = p0 + 1;
                const int i0 = 2 * j, i1 = i0 + 1;     // compile-time
                const int buf = j & 1;
                if (w == it) {
                    float x0 = m[i0], x1 = m[i1];
                    // 2x2 pivot block inverse (SPD principal block, det>0)
                    float a  = rl(x0, p0), bq = rl(x0, p1);
                    float cq = rl(x1, p0), dq = rl(x1, p1);
                    float dinv = 1.0f / (a * dq - bq * cq);
                    float P00 =  dq * dinv, P01 = -bq * dinv;
                    float P10 = -cq * dinv, P11 =  a  * dinv;
                    float sp0 = P00 * x0 + P01 * x1;
                    float sp1 = P10 * x0 + P11 * x1;
                    sp0 = (c == p0) ? P00 : ((c == p1) ? P01 : sp0);
                    sp1 = (c == p0) ? P10 : ((c == p1) ? P11 : sp1);
                    m[i0] = sp0; m[i1] = sp1;
                    prow[buf][0][c] = sp0;
                    prow[buf][1][c] = sp1;
                }
                __syncthreads();
                float s0  = prow[buf][0][c],  s1  = prow[buf][1][c];
                float q00 = prow[buf][0][p0], q01 = prow[buf][0][p1];
                float q10 = prow[buf][1][p0], q11 = prow[buf][1][p1];
                #pragma unroll
                for (int i = 0; i < 8; ++i) {
                    bool pivotRow = (w == it) && (i == i0 || i == i1);
                    float f0 = rl(m[i], p0);
                    float f1 = rl(m[i], p1);
                    float nv = m[i] - f0 * s0 - f1 * s1;
                    float wb0 = -(f0 * q00 + f1 * q10);
                    float wb1 = -(f0 * q01 + f1 * q11);
                    nv = (c == p0) ? wb0 : ((c == p1) ? wb1 : nv);
                    if (!pivotRow) m[i] = nv;
                }
            }
        }
        #pragma unroll
        for (int i = 0; i < 8; ++i)
            Kinv[(w * 8 + i) * 64 + c] = m[i];
        if (tid == 0) out[0] = 0.0f;     // init for K3's atomicAdd
    } else {
        // ---- L items: (b-1)*8 + wv in [0, 4128), exactly one per wave ----
        int item = (b - 1) * 8 + wv;
        int g, loc;
        if (item < 1040)      { g = 1; loc = item; }
        else if (item < 2080) { g = 2; loc = item - 1040; }
        else                  { g = 3; loc = item - 2080; }
        pde_item(g, loc, x, y, z, ws, &XiS[2 * wv], &incS[2 * wv]);
    }
}

// ---------------------------------------------------------------------------
// K3: block i computes W[i][:] = Kinv[i][:] - (Kinv^2)[i][:], dotted with
// L[:,i] (r3-proven); lane 0 atomicAdds into out (zeroed by K2 block 0).
// ---------------------------------------------------------------------------
__global__ __launch_bounds__(64)
void trace_kernel(const float* __restrict__ ws, float* __restrict__ out) {
    const int i    = blockIdx.x;
    const int lane = threadIdx.x;
    const float* Lg   = ws + 4096;
    const float* Lt   = ws + 8192;
    const float* Lm   = ws + 12288;
    const float* Kinv = ws + 16384;

    float u = Kinv[i * 64 + lane];
    float acc = 0.0f;
    #pragma unroll 8
    for (int k = 0; k < 64; ++k)
        acc = fmaf(__shfl(u, k), Kinv[k * 64 + lane], acc);   // (Kinv^2)[i][lane]
    float wv = u - acc;

    float lc = Lg[lane * 64 + i] + Lt[lane * 64 + i] - 2.0f * Lm[lane * 64 + i];
    float local = wv * lc;
    #pragma unroll
    for (int off = 32; off > 0; off >>= 1)
        local += __shfl_down(local, off);
    if (lane == 0) atomicAdd(out, local);
}

extern "C" void kernel_launch(void* const* d_in, const int* in_sizes, int n_in,
                              void* d_out, int out_size, void* d_ws, size_t ws_size,
                              hipStream_t stream) {
    const float* x = (const float*)d_in[0];
    const float* y = (const float*)d_in[1];
    const float* z = (const float*)d_in[2];
    float* out = (float*)d_out;
    float* ws  = (float*)d_ws;      // 20480 floats = 80 KB used

    pdeK_kernel<<<1040, 64, 0, stream>>>(x, y, z, ws);
    pdeL_gj_kernel<<<517, 512, 0, stream>>>(x, y, z, ws, out);
    trace_kernel<<<64, 64, 0, stream>>>(ws, out);
}